// Round 1
// baseline (426.467 us; speedup 1.0000x reference)
//
#include <hip/hip_runtime.h>

#define BATCH 65536
#define SEQ   64
#define INF   16
#define HS    10
#define OUTF  5

// One thread per batch row. x slice per thread = contiguous 4 KB.
// W1 lives in VGPRs (grid limits occupancy to 1 wave/SIMD anyway -> spend regs).
// Depth-4 float4x4 register prefetch hides HBM latency.
__global__ __launch_bounds__(256, 1) void rnn_fused(
    const float* __restrict__ x,  const float* __restrict__ W1,
    const float* __restrict__ b1, const float* __restrict__ W2,
    const float* __restrict__ b2, float* __restrict__ out)
{
    const int b = blockIdx.x * 256 + threadIdx.x;

    // Wave-uniform weights -> registers (one-time broadcast load via cache)
    float w1[INF * HS];
#pragma unroll
    for (int k = 0; k < INF * HS; ++k) w1[k] = W1[k];
    float bb1[HS];
#pragma unroll
    for (int h = 0; h < HS; ++h) bb1[h] = b1[h];

    float hreg[HS];
#pragma unroll
    for (int h = 0; h < HS; ++h) hreg[h] = 0.0f;

    const float4* __restrict__ xr =
        reinterpret_cast<const float4*>(x + (size_t)b * (SEQ * INF));

    // depth-4 prefetch pipeline: rows s..s+3 resident
    float4 buf[4][4];
#pragma unroll
    for (int r = 0; r < 4; ++r)
#pragma unroll
        for (int j = 0; j < 4; ++j) buf[r][j] = xr[r * 4 + j];

#pragma unroll 4
    for (int s = 0; s < SEQ; ++s) {
        const int slot = s & 3;
        float xv[INF];
#pragma unroll
        for (int j = 0; j < 4; ++j) {
            xv[j * 4 + 0] = buf[slot][j].x;
            xv[j * 4 + 1] = buf[slot][j].y;
            xv[j * 4 + 2] = buf[slot][j].z;
            xv[j * 4 + 3] = buf[slot][j].w;
        }
        // clamped prefetch (re-reads row 63 near tail: L1 hit, no divergence)
        const int pf = (s + 4 < SEQ) ? (s + 4) : (SEQ - 1);
#pragma unroll
        for (int j = 0; j < 4; ++j) buf[slot][j] = xr[pf * 4 + j];

        float a[HS];
#pragma unroll
        for (int h = 0; h < HS; ++h) a[h] = bb1[h];
#pragma unroll
        for (int i = 0; i < INF; ++i)
#pragma unroll
            for (int h = 0; h < HS; ++h)
                a[h] = fmaf(xv[i], w1[i * HS + h], a[h]);

#pragma unroll
        for (int h = 0; h < HS; ++h) {
            float t = hreg[h] + a[h];
            float e = __expf(2.0f * t);        // tanh(t) = 1 - 2/(e^(2t)+1)
            hreg[h] = 1.0f - 2.0f / (e + 1.0f); // correct limits at +/-inf
        }
    }

    // epilogue: y = sigmoid(h @ W2 + b2)   (W2/b2 loaded only here -> not live in loop)
    float y[OUTF];
#pragma unroll
    for (int o = 0; o < OUTF; ++o) y[o] = b2[o];
#pragma unroll
    for (int h = 0; h < HS; ++h)
#pragma unroll
        for (int o = 0; o < OUTF; ++o)
            y[o] = fmaf(hreg[h], W2[h * OUTF + o], y[o]);

    float* op = out + (size_t)b * OUTF;
#pragma unroll
    for (int o = 0; o < OUTF; ++o)
        op[o] = 1.0f / (1.0f + __expf(-y[o]));
}

extern "C" void kernel_launch(void* const* d_in, const int* in_sizes, int n_in,
                              void* d_out, int out_size, void* d_ws, size_t ws_size,
                              hipStream_t stream) {
    const float* x  = (const float*)d_in[0];
    const float* W1 = (const float*)d_in[1];
    const float* b1 = (const float*)d_in[2];
    const float* W2 = (const float*)d_in[3];
    const float* b2 = (const float*)d_in[4];
    float* out = (float*)d_out;

    rnn_fused<<<BATCH / 256, 256, 0, stream>>>(x, W1, b1, W2, b2, out);
}